// Round 1
// baseline (2722.409 us; speedup 1.0000x reference)
//
#include <hip/hip_runtime.h>

#define B_    16384
#define NPTS  4096
#define LAT   64
#define KCB   1024

// ---------------------------------------------------------------------------
// Generic fp32 tiled GEMM: C = act(A[M,K] @ W[K,N] + bias[N])
// BM=BN=64, BK=16, 256 threads, 4x4 micro-tile per thread.
// Optional fused squared-error reduction vs X (for dec3 recon loss).
// ---------------------------------------------------------------------------
template<bool RELU, bool FUSE_LOSS>
__global__ __launch_bounds__(256)
void gemm_kernel(const float* __restrict__ A, const float* __restrict__ W,
                 const float* __restrict__ bias, float* __restrict__ C,
                 int M, int N, int Kd,
                 const float* __restrict__ X, float* __restrict__ loss_acc)
{
    const int BM = 64, BN = 64, BK = 16;
    __shared__ float As[BK][BM + 4];   // stride 68: 16B-aligned float4 rows
    __shared__ float Bs[BK][BN + 4];

    const int tid = threadIdx.x;
    const int tx = tid & 15;          // 0..15 -> 4 cols each
    const int ty = tid >> 4;          // 0..15 -> 4 rows each
    const int m0 = blockIdx.y * BM;
    const int n0 = blockIdx.x * BN;

    float acc[4][4] = {};

    for (int k0 = 0; k0 < Kd; k0 += BK) {
        // A tile: 64 rows x 16 k  (256 float4 loads, transpose into As[k][m])
        {
            const int r  = tid >> 2;   // 0..63
            const int c4 = tid & 3;    // 0..3
            const float4 a4 = *(const float4*)(A + (size_t)(m0 + r) * Kd + k0 + c4 * 4);
            As[c4 * 4 + 0][r] = a4.x;
            As[c4 * 4 + 1][r] = a4.y;
            As[c4 * 4 + 2][r] = a4.z;
            As[c4 * 4 + 3][r] = a4.w;
        }
        // W tile: 16 k x 64 cols (contiguous float4 stores)
        {
            const int r  = tid >> 4;   // 0..15
            const int c4 = tid & 15;   // 0..15
            const float4 b4 = *(const float4*)(W + (size_t)(k0 + r) * N + n0 + c4 * 4);
            *(float4*)&Bs[r][c4 * 4] = b4;
        }
        __syncthreads();

        #pragma unroll
        for (int kk = 0; kk < BK; ++kk) {
            const float4 a4 = *(const float4*)&As[kk][ty * 4];
            const float4 b4 = *(const float4*)&Bs[kk][tx * 4];
            const float av[4] = {a4.x, a4.y, a4.z, a4.w};
            const float bv[4] = {b4.x, b4.y, b4.z, b4.w};
            #pragma unroll
            for (int i = 0; i < 4; ++i)
                #pragma unroll
                for (int j = 0; j < 4; ++j)
                    acc[i][j] += av[i] * bv[j];
        }
        __syncthreads();
    }

    float lsum = 0.f;
    #pragma unroll
    for (int i = 0; i < 4; ++i) {
        const int m = m0 + ty * 4 + i;
        #pragma unroll
        for (int j = 0; j < 4; ++j) {
            const int n = n0 + tx * 4 + j;
            float v = acc[i][j] + bias[n];
            if (RELU) v = fmaxf(v, 0.f);
            C[(size_t)m * N + n] = v;
            if (FUSE_LOSS) {
                const float d = v - X[(size_t)m * N + n];
                lsum += d * d;
            }
        }
    }

    if (FUSE_LOSS) {
        __shared__ float red[256];
        red[tid] = lsum;
        __syncthreads();
        for (int s = 128; s > 0; s >>= 1) {
            if (tid < s) red[tid] += red[tid + s];
            __syncthreads();
        }
        if (tid == 0) atomicAdd(loss_acc, red[0]);
    }
}

// ---------------------------------------------------------------------------
// Codebook squared norms: sc[c] = |codebook[c]|^2
// ---------------------------------------------------------------------------
__global__ __launch_bounds__(256)
void cbnorm_kernel(const float* __restrict__ cb, float* __restrict__ sc)
{
    const int c = blockIdx.x * blockDim.x + threadIdx.x;
    if (c < KCB) {
        double s = 0.0;
        #pragma unroll 16
        for (int j = 0; j < LAT; ++j) {
            const float v = cb[(size_t)c * LAT + j];
            s += (double)v * (double)v;
        }
        sc[c] = (float)s;
    }
}

// ---------------------------------------------------------------------------
// VQ assignment: one block per row. d = (S - 2*z.c) + |c|^2, argmin with
// lowest-index tie-break (matches jnp.argmin). Writes idx (as float) and zq.
// The fp64 dot is rounded to fp32 before the subtraction to reproduce the
// reference's fp32 quantization at magnitude |z|^2.
// ---------------------------------------------------------------------------
__global__ __launch_bounds__(256)
void vq_assign_kernel(const float* __restrict__ z, const float* __restrict__ cb,
                      const float* __restrict__ sc, float* __restrict__ zq,
                      float* __restrict__ idx_out)
{
    __shared__ float zrow[LAT];
    __shared__ float sS;
    __shared__ float rd[256];
    __shared__ int   ri[256];

    const int row = blockIdx.x;
    const int tid = threadIdx.x;

    if (tid < LAT) zrow[tid] = z[(size_t)row * LAT + tid];
    __syncthreads();
    if (tid == 0) {
        double s = 0.0;
        for (int j = 0; j < LAT; ++j) s += (double)zrow[j] * (double)zrow[j];
        sS = (float)s;
    }
    __syncthreads();
    const float S = sS;

    float bestd = 1e30f;
    int   besti = KCB;
    for (int c = tid; c < KCB; c += 256) {
        const float4* cb4 = (const float4*)(cb + (size_t)c * LAT);
        const float4* z4  = (const float4*)zrow;
        double dot = 0.0;
        #pragma unroll
        for (int q = 0; q < LAT / 4; ++q) {
            const float4 cv = cb4[q];
            const float4 zv = z4[q];
            dot += (double)zv.x * cv.x + (double)zv.y * cv.y
                 + (double)zv.z * cv.z + (double)zv.w * cv.w;
        }
        const float zc = (float)dot;
        const float d  = (S - 2.0f * zc) + sc[c];
        if (d < bestd || (d == bestd && c < besti)) { bestd = d; besti = c; }
    }

    rd[tid] = bestd; ri[tid] = besti;
    __syncthreads();
    for (int s = 128; s > 0; s >>= 1) {
        if (tid < s) {
            const float od = rd[tid + s];
            const int   oi = ri[tid + s];
            if (od < rd[tid] || (od == rd[tid] && oi < ri[tid])) {
                rd[tid] = od; ri[tid] = oi;
            }
        }
        __syncthreads();
    }
    const int best = ri[0];
    if (tid == 0) idx_out[row] = (float)best;
    if (tid < LAT) zq[(size_t)row * LAT + tid] = cb[(size_t)best * LAT + tid];
}

// ---------------------------------------------------------------------------
// vq partial: sum over (zq - z)^2 -> atomicAdd into acc
// ---------------------------------------------------------------------------
__global__ __launch_bounds__(256)
void vq_loss_kernel(const float* __restrict__ z, const float* __restrict__ zq,
                    float* __restrict__ acc, int n)
{
    float s = 0.f;
    for (int i = blockIdx.x * blockDim.x + threadIdx.x; i < n;
         i += gridDim.x * blockDim.x) {
        const float d = zq[i] - z[i];
        s += d * d;
    }
    __shared__ float red[256];
    red[threadIdx.x] = s;
    __syncthreads();
    for (int t = 128; t > 0; t >>= 1) {
        if (threadIdx.x < t) red[threadIdx.x] += red[threadIdx.x + t];
        __syncthreads();
    }
    if (threadIdx.x == 0) atomicAdd(acc, red[0]);
}

// ---------------------------------------------------------------------------
// finalize: write [total, recon, vq] scalars
// ---------------------------------------------------------------------------
__global__ void finalize_kernel(const float* __restrict__ acc, float* __restrict__ out3)
{
    const float recon = acc[0] / ((float)B_ * (float)NPTS);
    const float vq    = 1.25f * (acc[1] / ((float)B_ * (float)LAT));
    out3[0] = recon + vq;
    out3[1] = recon;
    out3[2] = vq;
}

// ---------------------------------------------------------------------------
extern "C" void kernel_launch(void* const* d_in, const int* in_sizes, int n_in,
                              void* d_out, int out_size, void* d_ws, size_t ws_size,
                              hipStream_t stream)
{
    const float* x   = (const float*)d_in[0];
    const float* ew1 = (const float*)d_in[1];
    const float* eb1 = (const float*)d_in[2];
    const float* ew2 = (const float*)d_in[3];
    const float* eb2 = (const float*)d_in[4];
    const float* ew3 = (const float*)d_in[5];
    const float* eb3 = (const float*)d_in[6];
    const float* cb  = (const float*)d_in[7];
    const float* dw1 = (const float*)d_in[8];
    const float* db1 = (const float*)d_in[9];
    const float* dw2 = (const float*)d_in[10];
    const float* db2 = (const float*)d_in[11];
    const float* dw3 = (const float*)d_in[12];
    const float* db3 = (const float*)d_in[13];

    float* out_xh     = (float*)d_out;                  // [B, NPTS]
    float* out_idx    = out_xh + (size_t)B_ * NPTS;     // [B] as float
    float* out_losses = out_idx + B_;                   // [3]

    float* ws   = (float*)d_ws;
    float* bufA = ws;                                   // h1 [B,512], reused as h4
    float* bufB = bufA + (size_t)B_ * 512;              // h2 [B,256], reused as h3
    float* z    = bufB + (size_t)B_ * 256;              // [B,64]
    float* zq   = z + (size_t)B_ * LAT;                 // [B,64]
    float* sc   = zq + (size_t)B_ * LAT;                // [KCB]
    float* acc  = sc + KCB;                             // [2]: recon_sum, vq_sum

    hipMemsetAsync(acc, 0, 2 * sizeof(float), stream);

    const dim3 blk(256);

    // encoder
    gemm_kernel<true,  false><<<dim3(512 / 64, B_ / 64), blk, 0, stream>>>(
        x, ew1, eb1, bufA, B_, 512, NPTS, nullptr, nullptr);
    gemm_kernel<true,  false><<<dim3(256 / 64, B_ / 64), blk, 0, stream>>>(
        bufA, ew2, eb2, bufB, B_, 256, 512, nullptr, nullptr);
    gemm_kernel<false, false><<<dim3(64 / 64,  B_ / 64), blk, 0, stream>>>(
        bufB, ew3, eb3, z, B_, 64, 256, nullptr, nullptr);

    // vector quantization
    cbnorm_kernel<<<dim3(KCB / 256), blk, 0, stream>>>(cb, sc);
    vq_assign_kernel<<<dim3(B_), blk, 0, stream>>>(z, cb, sc, zq, out_idx);
    vq_loss_kernel<<<dim3(256), blk, 0, stream>>>(z, zq, acc + 1, B_ * LAT);

    // decoder
    gemm_kernel<true,  false><<<dim3(256 / 64, B_ / 64), blk, 0, stream>>>(
        zq, dw1, db1, bufB, B_, 256, LAT, nullptr, nullptr);
    gemm_kernel<true,  false><<<dim3(512 / 64, B_ / 64), blk, 0, stream>>>(
        bufB, dw2, db2, bufA, B_, 512, 256, nullptr, nullptr);
    gemm_kernel<false, true ><<<dim3(NPTS / 64, B_ / 64), blk, 0, stream>>>(
        bufA, dw3, db3, out_xh, B_, NPTS, 512, x, acc + 0);

    finalize_kernel<<<1, 1, 0, stream>>>(acc, out_losses);
}